// Round 14
// baseline (537.915 us; speedup 1.0000x reference)
//
#include <hip/hip_runtime.h>
#include <hip/hip_bf16.h>
#include <stdint.h>

typedef __bf16 bf16x8 __attribute__((ext_vector_type(8)));
typedef __bf16 bf16x4 __attribute__((ext_vector_type(4)));
typedef float  f32x4  __attribute__((ext_vector_type(4)));

#define B_  16
#define KL  4096
#define D_  1024
#define NH  16
#define NROWS (B_*KL)   // 65536

__device__ __forceinline__ void gload_lds16(const void* g, void* l) {
  __builtin_amdgcn_global_load_lds(
      (__attribute__((address_space(1))) void*)g,
      (__attribute__((address_space(3))) void*)l, 16, 0, 0);
}

// ---------- small prep kernels ----------

__global__ __launch_bounds__(256) void conv_bf16_kernel(const float* __restrict__ s,
                                                        __bf16* __restrict__ d, int n4) {
  int i = blockIdx.x * 256 + threadIdx.x;
  if (i >= n4) return;
  float4 v = reinterpret_cast<const float4*>(s)[i];
  bf16x4 o;
  o[0] = (__bf16)v.x; o[1] = (__bf16)v.y; o[2] = (__bf16)v.z; o[3] = (__bf16)v.w;
  *reinterpret_cast<bf16x4*>(d + (size_t)i * 4) = o;
}

// q[b][j] = (hs[b,:]·Wq[j,:] + bq[j]) / 8
__global__ __launch_bounds__(256) void qproj_kernel(const float* __restrict__ hs,
                                                    const float* __restrict__ Wq,
                                                    const float* __restrict__ bq,
                                                    float* __restrict__ q) {
  int gid = blockIdx.x * 256 + threadIdx.x;   // 0..16383
  int b = gid >> 10, j = gid & 1023;
  const float* x = hs + (size_t)b * D_;
  const float* w = Wq + (size_t)j * D_;
  float acc = 0.f;
  for (int i = 0; i < D_; i += 4) {
    float4 xv = *reinterpret_cast<const float4*>(x + i);
    float4 wv = *reinterpret_cast<const float4*>(w + i);
    acc += xv.x*wv.x + xv.y*wv.y + xv.z*wv.z + xv.w*wv.w;
  }
  q[gid] = (acc + bq[j]) * 0.125f;
}

// wq_eff[b,h,m] = sum_d q[b,h*64+d] * Wk[h*64+d, m], emitted as bf16 hi/lo
// split (whi = bf16(x), wlo = bf16(x - whi)); cb[b,h] = sum_d q*bk.
__global__ __launch_bounds__(256) void wqeff_kernel(const float* __restrict__ q,
                                                    const float* __restrict__ Wk,
                                                    const float* __restrict__ bk,
                                                    __bf16* __restrict__ whi,
                                                    __bf16* __restrict__ wlo,
                                                    float* __restrict__ cb) {
  const int h = blockIdx.x, b = blockIdx.y;
  const int tid = threadIdx.x;
  __shared__ float ql[64];
  if (tid < 64) ql[tid] = q[(size_t)b * D_ + h * 64 + tid];
  __syncthreads();
  float a0 = 0, a1 = 0, a2 = 0, a3 = 0;
  for (int d = 0; d < 64; ++d) {
    float qv = ql[d];
    const float* wr = Wk + (size_t)(h * 64 + d) * D_;
    a0 += qv * wr[tid];
    a1 += qv * wr[tid + 256];
    a2 += qv * wr[tid + 512];
    a3 += qv * wr[tid + 768];
  }
  const size_t base = ((size_t)b * NH + h) * D_;
  float a[4] = {a0, a1, a2, a3};
#pragma unroll
  for (int j = 0; j < 4; ++j) {
    __bf16 hi = (__bf16)a[j];
    whi[base + j * 256 + tid] = hi;
    wlo[base + j * 256 + tid] = (__bf16)(a[j] - (float)hi);
  }
  if (tid < 64) {
    float p = ql[tid] * bk[h * 64 + tid];
    p += __shfl_down(p, 32); p += __shfl_down(p, 16); p += __shfl_down(p, 8);
    p += __shfl_down(p, 4);  p += __shfl_down(p, 2);  p += __shfl_down(p, 1);
    if (tid == 0) cb[b * NH + h] = p;
  }
}

// Scores via split-bf16 MFMA: score = k_hi·w_hi + (k_hi·w_lo + k_lo·w_hi).
// Software-pipelined: next iteration's kvs float4s are issued before this
// iteration's MFMAs; two accumulators break the dependent-MFMA chain.
// Also stores k_hi == bf16(kvs) as kvsB. One wave = 16 rows x 16 heads.
__global__ __launch_bounds__(256) void scores_mfma_kernel(
    const float* __restrict__ kvs,   // [B, KL, D]
    const __bf16* __restrict__ whi,  // [B*NH, D]
    const __bf16* __restrict__ wlo,  // [B*NH, D]
    const float* __restrict__ cb,    // [B*NH]
    float* __restrict__ attn,        // [B*KL, NH]
    __bf16* __restrict__ kvd) {      // [B*KL, D]
  const int b = blockIdx.y;
  const int tid = threadIdx.x;
  const int lane = tid & 63, wv = tid >> 6;       // 4 waves/block
  const int r16 = lane & 15, kgrp = lane >> 4;
  const int row0 = blockIdx.x * 64 + wv * 16;     // 16 rows per wave
  const size_t grow = (size_t)b * KL + row0;

  const float* xrow = kvs + (grow + r16) * D_ + kgrp * 8;
  __bf16*      krow = kvd + (grow + r16) * D_ + kgrp * 8;
  const __bf16* wh = whi + ((size_t)b * NH + r16) * D_ + kgrp * 8;
  const __bf16* wl = wlo + ((size_t)b * NH + r16) * D_ + kgrp * 8;

  f32x4 acc0 = {}, acc1 = {};
  float4 x0 = *reinterpret_cast<const float4*>(xrow);
  float4 x1 = *reinterpret_cast<const float4*>(xrow + 4);
  for (int k0 = 0; k0 < D_; k0 += 32) {
    float4 n0, n1;
    if (k0 + 32 < D_) {
      n0 = *reinterpret_cast<const float4*>(xrow + k0 + 32);
      n1 = *reinterpret_cast<const float4*>(xrow + k0 + 36);
    }
    bf16x8 bh = *reinterpret_cast<const bf16x8*>(wh + k0);
    bf16x8 bl = *reinterpret_cast<const bf16x8*>(wl + k0);
    float xs[8] = {x0.x, x0.y, x0.z, x0.w, x1.x, x1.y, x1.z, x1.w};
    bf16x8 hi, lo;
#pragma unroll
    for (int i = 0; i < 8; ++i) {
      __bf16 h = (__bf16)xs[i];
      hi[i] = h;
      lo[i] = (__bf16)(xs[i] - (float)h);
    }
    *reinterpret_cast<bf16x8*>(krow + k0) = hi;   // kvsB = bf16(kvs), exact
    acc0 = __builtin_amdgcn_mfma_f32_16x16x32_bf16(hi, bh, acc0, 0, 0, 0);
    acc1 = __builtin_amdgcn_mfma_f32_16x16x32_bf16(hi, bl, acc1, 0, 0, 0);
    acc1 = __builtin_amdgcn_mfma_f32_16x16x32_bf16(lo, bh, acc1, 0, 0, 0);
    x0 = n0; x1 = n1;
  }
  const float c = cb[b * NH + r16];               // head = r16 in C layout
#pragma unroll
  for (int r = 0; r < 4; ++r) {
    const int orow = row0 + kgrp * 4 + r;
    float s = acc0[r] + acc1[r] + c;
    attn[((size_t)b * KL + orow) * NH + r16] = fminf(fmaxf(s, 0.f), 1.f);
  }
}

// ---------- 256x256 / BK=64 bf16 MFMA GEMM, R12 4-phase skeleton ----------
// 512 threads = 8 waves (2M x 4N); wave tile 128x64. 2 barriers/K-tile.
// Stage placement (age-fixed vs R12): q1 stages B'h0+B'h1+A'h0 (6 loads),
// q2 stages A'h1 (2 loads). Ledger (per-thread, issue-ordered):
//   tile start: outstanding = Ah1(t) (2).
//   q1: +6 -> 8; vmcnt(6) retires Ah1(t) (age 4 phases); barrier -> q2's
//       ds_read of Ah1(t) safe.
//   q4-end: vmcnt(2) retires B'h0,B'h1,A'h0 (all staged in q1, age >= 3
//       phases ~ load latency); keeps A'h1 in flight -> invariant.
// Never vmcnt(0) mid-loop. T2 swizzle both-sides as verified in R7.
template <bool GATE>
__global__ __launch_bounds__(512, 2) void gemm_nt(const __bf16* __restrict__ A,
                                                  const __bf16* __restrict__ Bt,
                                                  const float* __restrict__ bias,
                                                  const float* __restrict__ gate,
                                                  void* __restrict__ Cp) {
  __shared__ __bf16 As[2][256 * 64];
  __shared__ __bf16 Bs[2][256 * 64];
  const int tid = threadIdx.x;
  const int lane = tid & 63, wid = tid >> 6;
  const int wm = wid >> 2, wn = wid & 3;           // 2 x 4 waves
  const int r16 = lane & 15, kgrp = lane >> 4;
  const int bswz = (blockIdx.x & 7) * 128 + (blockIdx.x >> 3);
  const int m0 = (bswz >> 2) * 256;
  const int n0 = (bswz & 3) * 256;

  const int srow = lane >> 3;
  const int scol = ((lane & 7) ^ srow) * 8;        // pre-swizzled source col

  const int sw0 = ((kgrp) ^ (r16 & 7)) * 8;
  const int sw1 = ((4 + kgrp) ^ (r16 & 7)) * 8;

  f32x4 acc[8][4] = {};   // [mh*4+f][nh*2+g]

#define STAGE_HALF(dstbuf, srcp, base0, h, k0)                                  \
  {                                                                             \
    _Pragma("unroll") for (int j = 0; j < 2; ++j) {                             \
      const int c = (h) * 16 + wid * 2 + j;                                     \
      gload_lds16((srcp) + (size_t)((base0) + c * 8 + srow) * D_ + (k0) + scol, \
                  &(dstbuf)[c * 512]);                                          \
    }                                                                           \
  }

#define LOAD_BV(Bb, sw)                                                         \
  _Pragma("unroll") for (int nh = 0; nh < 2; ++nh)                              \
    _Pragma("unroll") for (int g = 0; g < 2; ++g)                               \
      bv[nh * 2 + g] = *reinterpret_cast<const bf16x8*>(                        \
          &(Bb)[(nh * 128 + wn * 32 + g * 16 + r16) * 64 + (sw)]);

#define LOAD_AV(Ab, mh, sw)                                                     \
  _Pragma("unroll") for (int f = 0; f < 4; ++f)                                 \
    av[f] = *reinterpret_cast<const bf16x8*>(                                   \
        &(Ab)[((mh) * 128 + wm * 64 + f * 16 + r16) * 64 + (sw)]);

#define MFMA_PHASE(mh)                                                          \
  {                                                                             \
    __builtin_amdgcn_s_setprio(1);                                              \
    _Pragma("unroll") for (int f = 0; f < 4; ++f)                               \
      _Pragma("unroll") for (int q = 0; q < 4; ++q)                             \
        acc[(mh) * 4 + f][q] = __builtin_amdgcn_mfma_f32_16x16x32_bf16(         \
            av[f], bv[q], acc[(mh) * 4 + f][q], 0, 0, 0);                       \
    __builtin_amdgcn_s_setprio(0);                                              \
  }

  // prologue: tile 0 = Bh0,Bh1,Ah0,Ah1; retire all but Ah1(0).
  STAGE_HALF(Bs[0], Bt, n0, 0, 0);
  STAGE_HALF(Bs[0], Bt, n0, 1, 0);
  STAGE_HALF(As[0], A,  m0, 0, 0);
  STAGE_HALF(As[0], A,  m0, 1, 0);
  asm volatile("s_waitcnt vmcnt(2)" ::: "memory");
  __builtin_amdgcn_s_barrier();

  const int NT = D_ / 64;   // 16
  for (int t = 0; t < NT; ++t) {
    __bf16* Ab = (t & 1) ? As[1] : As[0];
    __bf16* Bb = (t & 1) ? Bs[1] : Bs[0];
    __bf16* An = (t & 1) ? As[0] : As[1];
    __bf16* Bn = (t & 1) ? Bs[0] : Bs[1];
    const int k1 = (t + 1) * 64;
    const bool pf = (t < NT - 1);
    bf16x8 bv[4], av[4];

    // ---- q1: (mh0, kk0); stage B'h0,B'h1,A'h0; retire Ah1(t) ----
    if (pf) {
      STAGE_HALF(Bn, Bt, n0, 0, k1);
      STAGE_HALF(Bn, Bt, n0, 1, k1);
      STAGE_HALF(An, A,  m0, 0, k1);
    }
    LOAD_BV(Bb, sw0);
    LOAD_AV(Ab, 0, sw0);
    MFMA_PHASE(0);
    if (pf) asm volatile("s_waitcnt vmcnt(6)" ::: "memory");
    else    asm volatile("s_waitcnt vmcnt(0)" ::: "memory");
    __builtin_amdgcn_s_barrier();
    // ---- q2: (mh1, kk0); stage A'h1 ----
    if (pf) STAGE_HALF(An, A, m0, 1, k1);
    LOAD_AV(Ab, 1, sw0);
    MFMA_PHASE(1);
    // ---- q3: (mh0, kk1) ----
    LOAD_BV(Bb, sw1);
    LOAD_AV(Ab, 0, sw1);
    MFMA_PHASE(0);
    // ---- q4: (mh1, kk1); retire B'+A'h0 (staged q1, age >= 3 phases) ----
    LOAD_AV(Ab, 1, sw1);
    MFMA_PHASE(1);
    if (pf) {
      asm volatile("s_waitcnt vmcnt(2)" ::: "memory");
      __builtin_amdgcn_s_barrier();
    }
  }

  // epilogue. C/D layout: col = lane&15, row = (lane>>4)*4 + reg
#pragma unroll
  for (int mh = 0; mh < 2; ++mh) {
#pragma unroll
    for (int f = 0; f < 4; ++f) {
      const int row0 = m0 + mh * 128 + wm * 64 + f * 16 + kgrp * 4;
#pragma unroll
      for (int nh = 0; nh < 2; ++nh) {
#pragma unroll
        for (int g = 0; g < 2; ++g) {
          const int col = n0 + nh * 128 + wn * 32 + g * 16 + r16;
          const float bc = bias[col];
          const int head = col >> 6;
          f32x4 v = acc[mh * 4 + f][nh * 2 + g];
#pragma unroll
          for (int r = 0; r < 4; ++r) {
            const int row = row0 + r;
            if constexpr (GATE) {
              float gg = gate[(size_t)row * NH + head];
              ((__bf16*)Cp)[(size_t)row * D_ + col] = (__bf16)((v[r] + bc) * gg);
            } else {
              ((float*)Cp)[(size_t)row * D_ + col] = v[r] + bc;
            }
          }
        }
      }
    }
  }
#undef STAGE_HALF
#undef LOAD_BV
#undef LOAD_AV
#undef MFMA_PHASE
}

extern "C" void kernel_launch(void* const* d_in, const int* in_sizes, int n_in,
                              void* d_out, int out_size, void* d_ws, size_t ws_size,
                              hipStream_t stream) {
  const float* hs  = (const float*)d_in[0];   // [16,1,1024]
  const float* kvs = (const float*)d_in[1];   // [16,4096,1024]
  const float* Wq  = (const float*)d_in[2];
  const float* bq  = (const float*)d_in[3];
  const float* Wk  = (const float*)d_in[4];
  const float* bk  = (const float*)d_in[5];
  const float* Wv  = (const float*)d_in[6];
  const float* bv  = (const float*)d_in[7];
  const float* Wo  = (const float*)d_in[8];
  const float* bo  = (const float*)d_in[9];
  float* out = (float*)d_out;

  char* w = (char*)d_ws;
  __bf16* ctx  = (__bf16*)w;  w += (size_t)NROWS * D_ * 2;    // 128 MB gated context (bf16)
  float*  attn = (float*)w;   w += (size_t)NROWS * NH * 4;    // 4 MB gate [row][head]
  __bf16* WvB  = (__bf16*)w;  w += (size_t)D_ * D_ * 2;       // 2 MB
  __bf16* WoB  = (__bf16*)w;  w += (size_t)D_ * D_ * 2;       // 2 MB
  __bf16* whi  = (__bf16*)w;  w += (size_t)B_ * NH * D_ * 2;  // 512 KB
  __bf16* wlo  = (__bf16*)w;  w += (size_t)B_ * NH * D_ * 2;  // 512 KB
  float*  qbuf = (float*)w;   w += (size_t)B_ * D_ * 4;       // 64 KB
  float*  cbuf = (float*)w;   w += B_ * NH * 4;               // 1 KB

  // bf16 copy of kvs lives in d_out (128 MB of its 256 MB); written by
  // scores_mfma (== bf16(kvs) exactly), consumed by GEMM1, then fully
  // overwritten by GEMM2's epilogue. No cross-call state.
  __bf16* kvsB = (__bf16*)d_out;

  conv_bf16_kernel<<<1024, 256, 0, stream>>>(Wv, WvB, 262144);
  conv_bf16_kernel<<<1024, 256, 0, stream>>>(Wo, WoB, 262144);
  qproj_kernel<<<64, 256, 0, stream>>>(hs, Wq, bq, qbuf);
  wqeff_kernel<<<dim3(NH, B_), 256, 0, stream>>>(qbuf, Wk, bk, whi, wlo, cbuf);
  scores_mfma_kernel<<<dim3(KL / 64, B_), 256, 0, stream>>>(kvs, whi, wlo, cbuf, attn, kvsB);
  gemm_nt<true ><<<1024, 512, 0, stream>>>(kvsB, WvB, bv, attn, ctx);
  gemm_nt<false><<<1024, 512, 0, stream>>>(ctx, WoB, bo, (const float*)nullptr, (void*)out);
}

// Round 15
// 476.545 us; speedup vs baseline: 1.1288x; 1.1288x over previous
//
#include <hip/hip_runtime.h>
#include <hip/hip_bf16.h>
#include <stdint.h>

typedef __bf16 bf16x8 __attribute__((ext_vector_type(8)));
typedef __bf16 bf16x4 __attribute__((ext_vector_type(4)));
typedef float  f32x4  __attribute__((ext_vector_type(4)));

#define B_  16
#define KL  4096
#define D_  1024
#define NH  16
#define NROWS (B_*KL)   // 65536

__device__ __forceinline__ void gload_lds16(const void* g, void* l) {
  __builtin_amdgcn_global_load_lds(
      (__attribute__((address_space(1))) void*)g,
      (__attribute__((address_space(3))) void*)l, 16, 0, 0);
}

// ---------- small prep kernels ----------

// Converts Wv (blocks 0..1023) and Wo (blocks 1024..2047) in one dispatch.
__global__ __launch_bounds__(256) void conv_w_kernel(const float* __restrict__ wv,
                                                     const float* __restrict__ wo,
                                                     __bf16* __restrict__ dv,
                                                     __bf16* __restrict__ do_) {
  const bool second = blockIdx.x >= 1024;
  const int i = (second ? blockIdx.x - 1024 : blockIdx.x) * 256 + threadIdx.x;
  const float* s = second ? wo : wv;
  __bf16* d = second ? do_ : dv;
  float4 v = reinterpret_cast<const float4*>(s)[i];
  bf16x4 o;
  o[0] = (__bf16)v.x; o[1] = (__bf16)v.y; o[2] = (__bf16)v.z; o[3] = (__bf16)v.w;
  *reinterpret_cast<bf16x4*>(d + (size_t)i * 4) = o;
}

// q[b][j] = (hs[b,:]·Wq[j,:] + bq[j]) / 8
__global__ __launch_bounds__(256) void qproj_kernel(const float* __restrict__ hs,
                                                    const float* __restrict__ Wq,
                                                    const float* __restrict__ bq,
                                                    float* __restrict__ q) {
  int gid = blockIdx.x * 256 + threadIdx.x;   // 0..16383
  int b = gid >> 10, j = gid & 1023;
  const float* x = hs + (size_t)b * D_;
  const float* w = Wq + (size_t)j * D_;
  float acc = 0.f;
  for (int i = 0; i < D_; i += 4) {
    float4 xv = *reinterpret_cast<const float4*>(x + i);
    float4 wv = *reinterpret_cast<const float4*>(w + i);
    acc += xv.x*wv.x + xv.y*wv.y + xv.z*wv.z + xv.w*wv.w;
  }
  q[gid] = (acc + bq[j]) * 0.125f;
}

// wq_eff[b,h,m] = sum_d q[b,h*64+d] * Wk[h*64+d, m], emitted as bf16 hi/lo
// split (whi = bf16(x), wlo = bf16(x - whi)); cb[b,h] = sum_d q*bk.
__global__ __launch_bounds__(256) void wqeff_kernel(const float* __restrict__ q,
                                                    const float* __restrict__ Wk,
                                                    const float* __restrict__ bk,
                                                    __bf16* __restrict__ whi,
                                                    __bf16* __restrict__ wlo,
                                                    float* __restrict__ cb) {
  const int h = blockIdx.x, b = blockIdx.y;
  const int tid = threadIdx.x;
  __shared__ float ql[64];
  if (tid < 64) ql[tid] = q[(size_t)b * D_ + h * 64 + tid];
  __syncthreads();
  float a0 = 0, a1 = 0, a2 = 0, a3 = 0;
  for (int d = 0; d < 64; ++d) {
    float qv = ql[d];
    const float* wr = Wk + (size_t)(h * 64 + d) * D_;
    a0 += qv * wr[tid];
    a1 += qv * wr[tid + 256];
    a2 += qv * wr[tid + 512];
    a3 += qv * wr[tid + 768];
  }
  const size_t base = ((size_t)b * NH + h) * D_;
  float a[4] = {a0, a1, a2, a3};
#pragma unroll
  for (int j = 0; j < 4; ++j) {
    __bf16 hi = (__bf16)a[j];
    whi[base + j * 256 + tid] = hi;
    wlo[base + j * 256 + tid] = (__bf16)(a[j] - (float)hi);
  }
  if (tid < 64) {
    float p = ql[tid] * bk[h * 64 + tid];
    p += __shfl_down(p, 32); p += __shfl_down(p, 16); p += __shfl_down(p, 8);
    p += __shfl_down(p, 4);  p += __shfl_down(p, 2);  p += __shfl_down(p, 1);
    if (tid == 0) cb[b * NH + h] = p;
  }
}

// Scores via split-bf16 MFMA: score = k_hi·w_hi + (k_hi·w_lo + k_lo·w_hi).
// K-unrolled by 2 with named prefetch regs (4 float4 = 64B/lane in flight)
// to cover HBM latency at the fixed 4-waves/SIMD parallelism.
// Also stores k_hi == bf16(kvs) as kvsB. One wave = 16 rows x 16 heads.
__global__ __launch_bounds__(256) void scores_mfma_kernel(
    const float* __restrict__ kvs,   // [B, KL, D]
    const __bf16* __restrict__ whi,  // [B*NH, D]
    const __bf16* __restrict__ wlo,  // [B*NH, D]
    const float* __restrict__ cb,    // [B*NH]
    float* __restrict__ attn,        // [B*KL, NH]
    __bf16* __restrict__ kvd) {      // [B*KL, D]
  const int b = blockIdx.y;
  const int tid = threadIdx.x;
  const int lane = tid & 63, wv = tid >> 6;       // 4 waves/block
  const int r16 = lane & 15, kgrp = lane >> 4;
  const int row0 = blockIdx.x * 64 + wv * 16;     // 16 rows per wave
  const size_t grow = (size_t)b * KL + row0;

  const float* xrow = kvs + (grow + r16) * D_ + kgrp * 8;
  __bf16*      krow = kvd + (grow + r16) * D_ + kgrp * 8;
  const __bf16* wh = whi + ((size_t)b * NH + r16) * D_ + kgrp * 8;
  const __bf16* wl = wlo + ((size_t)b * NH + r16) * D_ + kgrp * 8;

  f32x4 acc0 = {}, acc1 = {};

#define SPROC(xx0, xx1, kk)                                                     \
  {                                                                             \
    bf16x8 bh = *reinterpret_cast<const bf16x8*>(wh + (kk));                    \
    bf16x8 bl = *reinterpret_cast<const bf16x8*>(wl + (kk));                    \
    float xs[8] = {xx0.x, xx0.y, xx0.z, xx0.w, xx1.x, xx1.y, xx1.z, xx1.w};     \
    bf16x8 hi, lo;                                                              \
    _Pragma("unroll") for (int i = 0; i < 8; ++i) {                             \
      __bf16 h = (__bf16)xs[i];                                                 \
      hi[i] = h;                                                                \
      lo[i] = (__bf16)(xs[i] - (float)h);                                       \
    }                                                                           \
    *reinterpret_cast<bf16x8*>(krow + (kk)) = hi;                               \
    acc0 = __builtin_amdgcn_mfma_f32_16x16x32_bf16(hi, bh, acc0, 0, 0, 0);      \
    acc1 = __builtin_amdgcn_mfma_f32_16x16x32_bf16(hi, bl, acc1, 0, 0, 0);      \
    acc1 = __builtin_amdgcn_mfma_f32_16x16x32_bf16(lo, bh, acc1, 0, 0, 0);      \
  }

  float4 xa0 = *reinterpret_cast<const float4*>(xrow);
  float4 xa1 = *reinterpret_cast<const float4*>(xrow + 4);
  float4 xb0 = *reinterpret_cast<const float4*>(xrow + 32);
  float4 xb1 = *reinterpret_cast<const float4*>(xrow + 36);
  for (int k0 = 0; k0 < D_; k0 += 64) {
    float4 na0, na1, nb0, nb1;
    if (k0 + 64 < D_) {
      na0 = *reinterpret_cast<const float4*>(xrow + k0 + 64);
      na1 = *reinterpret_cast<const float4*>(xrow + k0 + 68);
      nb0 = *reinterpret_cast<const float4*>(xrow + k0 + 96);
      nb1 = *reinterpret_cast<const float4*>(xrow + k0 + 100);
    }
    SPROC(xa0, xa1, k0);
    SPROC(xb0, xb1, k0 + 32);
    xa0 = na0; xa1 = na1; xb0 = nb0; xb1 = nb1;
  }
#undef SPROC
  const float c = cb[b * NH + r16];               // head = r16 in C layout
#pragma unroll
  for (int r = 0; r < 4; ++r) {
    const int orow = row0 + kgrp * 4 + r;
    float s = acc0[r] + acc1[r] + c;
    attn[((size_t)b * KL + orow) * NH + r16] = fminf(fmaxf(s, 0.f), 1.f);
  }
}

// ---------- 256x256 / BK=64 bf16 MFMA GEMM, 8-barrier m201-style phases ----------
// EXACT R12 structure (best measured: 163-167 µs, MfmaUtil 35%).
// 512 threads = 8 waves (2M x 4N); wave tile 128x64. 4 phases/K-tile, each:
//   { ds_read subtile; stage 1 half-tile(t+1); barrier; lgkmcnt(0);
//     sched_barrier(0); setprio(1); 16 MFMA; setprio(0); [vmcnt]; barrier }
// Stage order per tile: p1:Bh0 p2:Bh1 p3:Ah0 p4:Ah1 (2 loads/thread each).
// Ledger: tile start outstanding = Ah1(t); p1 +Bh0'; vmcnt(2) retires Ah1(t);
// p4 +Ah1' -> 8 outstanding; vmcnt(2) retires B'+Ah0'. Never vmcnt(0) mid-loop.
template <bool GATE>
__global__ __launch_bounds__(512, 2) void gemm_nt(const __bf16* __restrict__ A,
                                                  const __bf16* __restrict__ Bt,
                                                  const float* __restrict__ bias,
                                                  const float* __restrict__ gate,
                                                  void* __restrict__ Cp) {
  __shared__ __bf16 As[2][256 * 64];
  __shared__ __bf16 Bs[2][256 * 64];
  const int tid = threadIdx.x;
  const int lane = tid & 63, wid = tid >> 6;
  const int wm = wid >> 2, wn = wid & 3;           // 2 x 4 waves
  const int r16 = lane & 15, kgrp = lane >> 4;
  const int bswz = (blockIdx.x & 7) * 128 + (blockIdx.x >> 3);
  const int m0 = (bswz >> 2) * 256;
  const int n0 = (bswz & 3) * 256;

  const int srow = lane >> 3;
  const int scol = ((lane & 7) ^ srow) * 8;        // pre-swizzled source col

  const int sw0 = ((kgrp) ^ (r16 & 7)) * 8;
  const int sw1 = ((4 + kgrp) ^ (r16 & 7)) * 8;

  f32x4 acc[8][4] = {};   // [mh*4+f][nh*2+g]

#define STAGE_HALF(dstbuf, srcp, base0, h, k0)                                  \
  {                                                                             \
    _Pragma("unroll") for (int j = 0; j < 2; ++j) {                             \
      const int c = (h) * 16 + wid * 2 + j;                                     \
      gload_lds16((srcp) + (size_t)((base0) + c * 8 + srow) * D_ + (k0) + scol, \
                  &(dstbuf)[c * 512]);                                          \
    }                                                                           \
  }

#define LOAD_BV(Bb, sw)                                                         \
  _Pragma("unroll") for (int nh = 0; nh < 2; ++nh)                              \
    _Pragma("unroll") for (int g = 0; g < 2; ++g)                               \
      bv[nh * 2 + g] = *reinterpret_cast<const bf16x8*>(                        \
          &(Bb)[(nh * 128 + wn * 32 + g * 16 + r16) * 64 + (sw)]);

#define LOAD_AV(Ab, mh, sw)                                                     \
  _Pragma("unroll") for (int f = 0; f < 4; ++f)                                 \
    av[f] = *reinterpret_cast<const bf16x8*>(                                   \
        &(Ab)[((mh) * 128 + wm * 64 + f * 16 + r16) * 64 + (sw)]);

#define MFMA_PHASE(mh)                                                          \
  {                                                                             \
    __builtin_amdgcn_s_setprio(1);                                              \
    _Pragma("unroll") for (int f = 0; f < 4; ++f)                               \
      _Pragma("unroll") for (int q = 0; q < 4; ++q)                             \
        acc[(mh) * 4 + f][q] = __builtin_amdgcn_mfma_f32_16x16x32_bf16(         \
            av[f], bv[q], acc[(mh) * 4 + f][q], 0, 0, 0);                       \
    __builtin_amdgcn_s_setprio(0);                                              \
  }

#define WAITLGKM()                                                              \
  asm volatile("s_waitcnt lgkmcnt(0)" ::: "memory");                            \
  __builtin_amdgcn_sched_barrier(0);

  // prologue: tile 0 = Bh0,Bh1,Ah0,Ah1; retire all but Ah1(0).
  STAGE_HALF(Bs[0], Bt, n0, 0, 0);
  STAGE_HALF(Bs[0], Bt, n0, 1, 0);
  STAGE_HALF(As[0], A,  m0, 0, 0);
  STAGE_HALF(As[0], A,  m0, 1, 0);
  asm volatile("s_waitcnt vmcnt(2)" ::: "memory");
  __builtin_amdgcn_s_barrier();

  const int NT = D_ / 64;   // 16
  for (int t = 0; t < NT; ++t) {
    __bf16* Ab = (t & 1) ? As[1] : As[0];
    __bf16* Bb = (t & 1) ? Bs[1] : Bs[0];
    __bf16* An = (t & 1) ? As[0] : As[1];
    __bf16* Bn = (t & 1) ? Bs[0] : Bs[1];
    const int k1 = (t + 1) * 64;
    const bool pf = (t < NT - 1);
    bf16x8 bv[4], av[4];

    // ---- p1: (mh0, kk0); stage Bh0(t+1); retire Ah1(t) ----
    LOAD_BV(Bb, sw0);
    LOAD_AV(Ab, 0, sw0);
    if (pf) STAGE_HALF(Bn, Bt, n0, 0, k1);
    __builtin_amdgcn_s_barrier();
    WAITLGKM();
    MFMA_PHASE(0);
    if (pf) asm volatile("s_waitcnt vmcnt(2)" ::: "memory");
    else    asm volatile("s_waitcnt vmcnt(0)" ::: "memory");
    __builtin_amdgcn_s_barrier();
    // ---- p2: (mh1, kk0); stage Bh1(t+1) ----
    LOAD_AV(Ab, 1, sw0);
    if (pf) STAGE_HALF(Bn, Bt, n0, 1, k1);
    __builtin_amdgcn_s_barrier();
    WAITLGKM();
    MFMA_PHASE(1);
    __builtin_amdgcn_s_barrier();
    // ---- p3: (mh0, kk1); stage Ah0(t+1) ----
    LOAD_BV(Bb, sw1);
    LOAD_AV(Ab, 0, sw1);
    if (pf) STAGE_HALF(An, A, m0, 0, k1);
    __builtin_amdgcn_s_barrier();
    WAITLGKM();
    MFMA_PHASE(0);
    __builtin_amdgcn_s_barrier();
    // ---- p4: (mh1, kk1); stage Ah1(t+1); retire B(t+1)+Ah0(t+1) ----
    LOAD_AV(Ab, 1, sw1);
    if (pf) STAGE_HALF(An, A, m0, 1, k1);
    __builtin_amdgcn_s_barrier();
    WAITLGKM();
    MFMA_PHASE(1);
    if (pf) asm volatile("s_waitcnt vmcnt(2)" ::: "memory");
    __builtin_amdgcn_s_barrier();
  }

  // epilogue. C/D layout: col = lane&15, row = (lane>>4)*4 + reg
#pragma unroll
  for (int mh = 0; mh < 2; ++mh) {
#pragma unroll
    for (int f = 0; f < 4; ++f) {
      const int row0 = m0 + mh * 128 + wm * 64 + f * 16 + kgrp * 4;
#pragma unroll
      for (int nh = 0; nh < 2; ++nh) {
#pragma unroll
        for (int g = 0; g < 2; ++g) {
          const int col = n0 + nh * 128 + wn * 32 + g * 16 + r16;
          const float bc = bias[col];
          const int head = col >> 6;
          f32x4 v = acc[mh * 4 + f][nh * 2 + g];
#pragma unroll
          for (int r = 0; r < 4; ++r) {
            const int row = row0 + r;
            if constexpr (GATE) {
              float gg = gate[(size_t)row * NH + head];
              ((__bf16*)Cp)[(size_t)row * D_ + col] = (__bf16)((v[r] + bc) * gg);
            } else {
              ((float*)Cp)[(size_t)row * D_ + col] = v[r] + bc;
            }
          }
        }
      }
    }
  }
#undef STAGE_HALF
#undef LOAD_BV
#undef LOAD_AV
#undef MFMA_PHASE
#undef WAITLGKM
}

extern "C" void kernel_launch(void* const* d_in, const int* in_sizes, int n_in,
                              void* d_out, int out_size, void* d_ws, size_t ws_size,
                              hipStream_t stream) {
  const float* hs  = (const float*)d_in[0];   // [16,1,1024]
  const float* kvs = (const float*)d_in[1];   // [16,4096,1024]
  const float* Wq  = (const float*)d_in[2];
  const float* bq  = (const float*)d_in[3];
  const float* Wk  = (const float*)d_in[4];
  const float* bk  = (const float*)d_in[5];
  const float* Wv  = (const float*)d_in[6];
  const float* bv  = (const float*)d_in[7];
  const float* Wo  = (const float*)d_in[8];
  const float* bo  = (const float*)d_in[9];
  float* out = (float*)d_out;

  char* w = (char*)d_ws;
  __bf16* ctx  = (__bf16*)w;  w += (size_t)NROWS * D_ * 2;    // 128 MB gated context (bf16)
  float*  attn = (float*)w;   w += (size_t)NROWS * NH * 4;    // 4 MB gate [row][head]
  __bf16* WvB  = (__bf16*)w;  w += (size_t)D_ * D_ * 2;       // 2 MB
  __bf16* WoB  = (__bf16*)w;  w += (size_t)D_ * D_ * 2;       // 2 MB
  __bf16* whi  = (__bf16*)w;  w += (size_t)B_ * NH * D_ * 2;  // 512 KB
  __bf16* wlo  = (__bf16*)w;  w += (size_t)B_ * NH * D_ * 2;  // 512 KB
  float*  qbuf = (float*)w;   w += (size_t)B_ * D_ * 4;       // 64 KB
  float*  cbuf = (float*)w;   w += B_ * NH * 4;               // 1 KB

  // bf16 copy of kvs lives in d_out (128 MB of its 256 MB); written by
  // scores_mfma (== bf16(kvs) exactly), consumed by GEMM1, then fully
  // overwritten by GEMM2's epilogue. No cross-call state.
  __bf16* kvsB = (__bf16*)d_out;

  conv_w_kernel<<<2048, 256, 0, stream>>>(Wv, Wo, WvB, WoB);
  qproj_kernel<<<64, 256, 0, stream>>>(hs, Wq, bq, qbuf);
  wqeff_kernel<<<dim3(NH, B_), 256, 0, stream>>>(qbuf, Wk, bk, whi, wlo, cbuf);
  scores_mfma_kernel<<<dim3(KL / 64, B_), 256, 0, stream>>>(kvs, whi, wlo, cbuf, attn, kvsB);
  gemm_nt<true ><<<1024, 512, 0, stream>>>(kvsB, WvB, bv, attn, ctx);
  gemm_nt<false><<<1024, 512, 0, stream>>>(ctx, WoB, bo, (const float*)nullptr, (void*)out);
}

// Round 16
// 443.479 us; speedup vs baseline: 1.2129x; 1.0746x over previous
//
#include <hip/hip_runtime.h>
#include <hip/hip_bf16.h>
#include <stdint.h>

typedef __bf16 bf16x8 __attribute__((ext_vector_type(8)));
typedef __bf16 bf16x4 __attribute__((ext_vector_type(4)));
typedef float  f32x4  __attribute__((ext_vector_type(4)));

#define B_  16
#define KL  4096
#define D_  1024
#define NH  16
#define NROWS (B_*KL)   // 65536

__device__ __forceinline__ void gload_lds16(const void* g, void* l) {
  __builtin_amdgcn_global_load_lds(
      (__attribute__((address_space(1))) void*)g,
      (__attribute__((address_space(3))) void*)l, 16, 0, 0);
}

// ---------- small prep kernels ----------

// Converts Wv (blocks 0..1023) and Wo (blocks 1024..2047) in one dispatch.
__global__ __launch_bounds__(256) void conv_w_kernel(const float* __restrict__ wv,
                                                     const float* __restrict__ wo,
                                                     __bf16* __restrict__ dv,
                                                     __bf16* __restrict__ do_) {
  const bool second = blockIdx.x >= 1024;
  const int i = (second ? blockIdx.x - 1024 : blockIdx.x) * 256 + threadIdx.x;
  const float* s = second ? wo : wv;
  __bf16* d = second ? do_ : dv;
  float4 v = reinterpret_cast<const float4*>(s)[i];
  bf16x4 o;
  o[0] = (__bf16)v.x; o[1] = (__bf16)v.y; o[2] = (__bf16)v.z; o[3] = (__bf16)v.w;
  *reinterpret_cast<bf16x4*>(d + (size_t)i * 4) = o;
}

// Fused q-projection + wq_eff. Block (h,b):
//   q[d] = (hs[b,:]·Wq[h*64+d,:] + bq[h*64+d])/8      (d = 0..63)
//   wq_eff[b,h,m] = sum_d q[d] * Wk[h*64+d, m]  -> bf16 hi/lo split
//   cb[b,h] = sum_d q[d]*bk[h*64+d]
__global__ __launch_bounds__(256) void wqeff_kernel(const float* __restrict__ hs,
                                                    const float* __restrict__ Wq,
                                                    const float* __restrict__ bq,
                                                    const float* __restrict__ Wk,
                                                    const float* __restrict__ bk,
                                                    __bf16* __restrict__ whi,
                                                    __bf16* __restrict__ wlo,
                                                    float* __restrict__ cb) {
  const int h = blockIdx.x, b = blockIdx.y;
  const int tid = threadIdx.x;
  __shared__ float hsl[D_];
  __shared__ float ql[64];
  {
    float4 v = reinterpret_cast<const float4*>(hs + (size_t)b * D_)[tid];
    hsl[tid * 4] = v.x; hsl[tid * 4 + 1] = v.y;
    hsl[tid * 4 + 2] = v.z; hsl[tid * 4 + 3] = v.w;
  }
  __syncthreads();
  {
    const int d = tid >> 2, seg = tid & 3;
    const float* wr = Wq + (size_t)(h * 64 + d) * D_ + seg * 256;
    const float* xs = hsl + seg * 256;
    float p = 0.f;
    for (int i = 0; i < 256; i += 4) {
      float4 wv4 = *reinterpret_cast<const float4*>(wr + i);
      p += xs[i] * wv4.x + xs[i + 1] * wv4.y + xs[i + 2] * wv4.z + xs[i + 3] * wv4.w;
    }
    p += __shfl_xor(p, 1);
    p += __shfl_xor(p, 2);
    if (seg == 0) ql[d] = (p + bq[h * 64 + d]) * 0.125f;
  }
  __syncthreads();
  float a0 = 0, a1 = 0, a2 = 0, a3 = 0;
  for (int d = 0; d < 64; ++d) {
    float qv = ql[d];
    const float* wr = Wk + (size_t)(h * 64 + d) * D_;
    a0 += qv * wr[tid];
    a1 += qv * wr[tid + 256];
    a2 += qv * wr[tid + 512];
    a3 += qv * wr[tid + 768];
  }
  const size_t base = ((size_t)b * NH + h) * D_;
  float a[4] = {a0, a1, a2, a3};
#pragma unroll
  for (int j = 0; j < 4; ++j) {
    __bf16 hi = (__bf16)a[j];
    whi[base + j * 256 + tid] = hi;
    wlo[base + j * 256 + tid] = (__bf16)(a[j] - (float)hi);
  }
  if (tid < 64) {
    float p = ql[tid] * bk[h * 64 + tid];
    p += __shfl_down(p, 32); p += __shfl_down(p, 16); p += __shfl_down(p, 8);
    p += __shfl_down(p, 4);  p += __shfl_down(p, 2);  p += __shfl_down(p, 1);
    if (tid == 0) cb[b * NH + h] = p;
  }
}

// Scores via split-bf16 MFMA, K-SPLIT x2 for latency hiding:
// block = 512 thr = 8 waves = 4 row-groups x 2 K-halves (512 elems each).
// Each wave: 16 rows x 16 heads over its K-half (8 pipelined iters).
// kh=1 waves deposit partials in LDS; kh=0 waves combine + gate + store.
// Also stores k_hi == bf16(kvs) as kvsB (each half covers its own span).
__global__ __launch_bounds__(512) void scores_mfma_kernel(
    const float* __restrict__ kvs,   // [B, KL, D]
    const __bf16* __restrict__ whi,  // [B*NH, D]
    const __bf16* __restrict__ wlo,  // [B*NH, D]
    const float* __restrict__ cb,    // [B*NH]
    float* __restrict__ attn,        // [B*KL, NH]
    __bf16* __restrict__ kvd) {      // [B*KL, D]
  __shared__ f32x4 part[4][64];
  const int b = blockIdx.y;
  const int tid = threadIdx.x;
  const int lane = tid & 63, wv = tid >> 6;       // 8 waves
  const int rg = wv & 3;                          // row-group 0..3
  const int kh = wv >> 2;                         // K-half 0/1
  const int r16 = lane & 15, kgrp = lane >> 4;
  const int row0 = blockIdx.x * 64 + rg * 16;
  const size_t grow = (size_t)b * KL + row0;
  const int kbase = kh * 512;

  const float* xrow = kvs + (grow + r16) * D_ + kbase + kgrp * 8;
  __bf16*      krow = kvd + (grow + r16) * D_ + kbase + kgrp * 8;
  const __bf16* wh = whi + ((size_t)b * NH + r16) * D_ + kbase + kgrp * 8;
  const __bf16* wl = wlo + ((size_t)b * NH + r16) * D_ + kbase + kgrp * 8;

  f32x4 acc0 = {}, acc1 = {};

#define SPROC(xx0, xx1, kk)                                                     \
  {                                                                             \
    bf16x8 bh = *reinterpret_cast<const bf16x8*>(wh + (kk));                    \
    bf16x8 bl = *reinterpret_cast<const bf16x8*>(wl + (kk));                    \
    float xs[8] = {xx0.x, xx0.y, xx0.z, xx0.w, xx1.x, xx1.y, xx1.z, xx1.w};     \
    bf16x8 hi, lo;                                                              \
    _Pragma("unroll") for (int i = 0; i < 8; ++i) {                             \
      __bf16 h = (__bf16)xs[i];                                                 \
      hi[i] = h;                                                                \
      lo[i] = (__bf16)(xs[i] - (float)h);                                       \
    }                                                                           \
    *reinterpret_cast<bf16x8*>(krow + (kk)) = hi;                               \
    acc0 = __builtin_amdgcn_mfma_f32_16x16x32_bf16(hi, bh, acc0, 0, 0, 0);      \
    acc1 = __builtin_amdgcn_mfma_f32_16x16x32_bf16(hi, bl, acc1, 0, 0, 0);      \
    acc1 = __builtin_amdgcn_mfma_f32_16x16x32_bf16(lo, bh, acc1, 0, 0, 0);      \
  }

  float4 xa0 = *reinterpret_cast<const float4*>(xrow);
  float4 xa1 = *reinterpret_cast<const float4*>(xrow + 4);
  float4 xb0 = *reinterpret_cast<const float4*>(xrow + 32);
  float4 xb1 = *reinterpret_cast<const float4*>(xrow + 36);
  for (int k0 = 0; k0 < 512; k0 += 64) {
    float4 na0, na1, nb0, nb1;
    if (k0 + 64 < 512) {
      na0 = *reinterpret_cast<const float4*>(xrow + k0 + 64);
      na1 = *reinterpret_cast<const float4*>(xrow + k0 + 68);
      nb0 = *reinterpret_cast<const float4*>(xrow + k0 + 96);
      nb1 = *reinterpret_cast<const float4*>(xrow + k0 + 100);
    }
    SPROC(xa0, xa1, k0);
    SPROC(xb0, xb1, k0 + 32);
    xa0 = na0; xa1 = na1; xb0 = nb0; xb1 = nb1;
  }
#undef SPROC

  if (kh == 1) {
    f32x4 s = acc0;
#pragma unroll
    for (int r = 0; r < 4; ++r) s[r] += acc1[r];
    part[rg][lane] = s;
  }
  __syncthreads();
  if (kh == 0) {
    f32x4 p = part[rg][lane];
    const float c = cb[b * NH + r16];             // head = r16 in C layout
#pragma unroll
    for (int r = 0; r < 4; ++r) {
      const int orow = row0 + kgrp * 4 + r;
      float s = acc0[r] + acc1[r] + p[r] + c;
      attn[((size_t)b * KL + orow) * NH + r16] = fminf(fmaxf(s, 0.f), 1.f);
    }
  }
}

// ---------- 256x256 / BK=64 bf16 MFMA GEMM, 8-barrier m201-style phases ----------
// EXACT R12/R15 structure (best measured; two modifications both regressed).
template <bool GATE>
__global__ __launch_bounds__(512, 2) void gemm_nt(const __bf16* __restrict__ A,
                                                  const __bf16* __restrict__ Bt,
                                                  const float* __restrict__ bias,
                                                  const float* __restrict__ gate,
                                                  void* __restrict__ Cp) {
  __shared__ __bf16 As[2][256 * 64];
  __shared__ __bf16 Bs[2][256 * 64];
  const int tid = threadIdx.x;
  const int lane = tid & 63, wid = tid >> 6;
  const int wm = wid >> 2, wn = wid & 3;           // 2 x 4 waves
  const int r16 = lane & 15, kgrp = lane >> 4;
  const int bswz = (blockIdx.x & 7) * 128 + (blockIdx.x >> 3);
  const int m0 = (bswz >> 2) * 256;
  const int n0 = (bswz & 3) * 256;

  const int srow = lane >> 3;
  const int scol = ((lane & 7) ^ srow) * 8;        // pre-swizzled source col

  const int sw0 = ((kgrp) ^ (r16 & 7)) * 8;
  const int sw1 = ((4 + kgrp) ^ (r16 & 7)) * 8;

  f32x4 acc[8][4] = {};   // [mh*4+f][nh*2+g]

#define STAGE_HALF(dstbuf, srcp, base0, h, k0)                                  \
  {                                                                             \
    _Pragma("unroll") for (int j = 0; j < 2; ++j) {                             \
      const int c = (h) * 16 + wid * 2 + j;                                     \
      gload_lds16((srcp) + (size_t)((base0) + c * 8 + srow) * D_ + (k0) + scol, \
                  &(dstbuf)[c * 512]);                                          \
    }                                                                           \
  }

#define LOAD_BV(Bb, sw)                                                         \
  _Pragma("unroll") for (int nh = 0; nh < 2; ++nh)                              \
    _Pragma("unroll") for (int g = 0; g < 2; ++g)                               \
      bv[nh * 2 + g] = *reinterpret_cast<const bf16x8*>(                        \
          &(Bb)[(nh * 128 + wn * 32 + g * 16 + r16) * 64 + (sw)]);

#define LOAD_AV(Ab, mh, sw)                                                     \
  _Pragma("unroll") for (int f = 0; f < 4; ++f)                                 \
    av[f] = *reinterpret_cast<const bf16x8*>(                                   \
        &(Ab)[((mh) * 128 + wm * 64 + f * 16 + r16) * 64 + (sw)]);

#define MFMA_PHASE(mh)                                                          \
  {                                                                             \
    __builtin_amdgcn_s_setprio(1);                                              \
    _Pragma("unroll") for (int f = 0; f < 4; ++f)                               \
      _Pragma("unroll") for (int q = 0; q < 4; ++q)                             \
        acc[(mh) * 4 + f][q] = __builtin_amdgcn_mfma_f32_16x16x32_bf16(         \
            av[f], bv[q], acc[(mh) * 4 + f][q], 0, 0, 0);                       \
    __builtin_amdgcn_s_setprio(0);                                              \
  }

#define WAITLGKM()                                                              \
  asm volatile("s_waitcnt lgkmcnt(0)" ::: "memory");                            \
  __builtin_amdgcn_sched_barrier(0);

  // prologue: tile 0 = Bh0,Bh1,Ah0,Ah1; retire all but Ah1(0).
  STAGE_HALF(Bs[0], Bt, n0, 0, 0);
  STAGE_HALF(Bs[0], Bt, n0, 1, 0);
  STAGE_HALF(As[0], A,  m0, 0, 0);
  STAGE_HALF(As[0], A,  m0, 1, 0);
  asm volatile("s_waitcnt vmcnt(2)" ::: "memory");
  __builtin_amdgcn_s_barrier();

  const int NT = D_ / 64;   // 16
  for (int t = 0; t < NT; ++t) {
    __bf16* Ab = (t & 1) ? As[1] : As[0];
    __bf16* Bb = (t & 1) ? Bs[1] : Bs[0];
    __bf16* An = (t & 1) ? As[0] : As[1];
    __bf16* Bn = (t & 1) ? Bs[0] : Bs[1];
    const int k1 = (t + 1) * 64;
    const bool pf = (t < NT - 1);
    bf16x8 bv[4], av[4];

    // ---- p1: (mh0, kk0); stage Bh0(t+1); retire Ah1(t) ----
    LOAD_BV(Bb, sw0);
    LOAD_AV(Ab, 0, sw0);
    if (pf) STAGE_HALF(Bn, Bt, n0, 0, k1);
    __builtin_amdgcn_s_barrier();
    WAITLGKM();
    MFMA_PHASE(0);
    if (pf) asm volatile("s_waitcnt vmcnt(2)" ::: "memory");
    else    asm volatile("s_waitcnt vmcnt(0)" ::: "memory");
    __builtin_amdgcn_s_barrier();
    // ---- p2: (mh1, kk0); stage Bh1(t+1) ----
    LOAD_AV(Ab, 1, sw0);
    if (pf) STAGE_HALF(Bn, Bt, n0, 1, k1);
    __builtin_amdgcn_s_barrier();
    WAITLGKM();
    MFMA_PHASE(1);
    __builtin_amdgcn_s_barrier();
    // ---- p3: (mh0, kk1); stage Ah0(t+1) ----
    LOAD_BV(Bb, sw1);
    LOAD_AV(Ab, 0, sw1);
    if (pf) STAGE_HALF(An, A, m0, 0, k1);
    __builtin_amdgcn_s_barrier();
    WAITLGKM();
    MFMA_PHASE(0);
    __builtin_amdgcn_s_barrier();
    // ---- p4: (mh1, kk1); stage Ah1(t+1); retire B(t+1)+Ah0(t+1) ----
    LOAD_AV(Ab, 1, sw1);
    if (pf) STAGE_HALF(An, A, m0, 1, k1);
    __builtin_amdgcn_s_barrier();
    WAITLGKM();
    MFMA_PHASE(1);
    if (pf) asm volatile("s_waitcnt vmcnt(2)" ::: "memory");
    __builtin_amdgcn_s_barrier();
  }

  // epilogue. C/D layout: col = lane&15, row = (lane>>4)*4 + reg
#pragma unroll
  for (int mh = 0; mh < 2; ++mh) {
#pragma unroll
    for (int f = 0; f < 4; ++f) {
      const int row0 = m0 + mh * 128 + wm * 64 + f * 16 + kgrp * 4;
#pragma unroll
      for (int nh = 0; nh < 2; ++nh) {
#pragma unroll
        for (int g = 0; g < 2; ++g) {
          const int col = n0 + nh * 128 + wn * 32 + g * 16 + r16;
          const float bc = bias[col];
          const int head = col >> 6;
          f32x4 v = acc[mh * 4 + f][nh * 2 + g];
#pragma unroll
          for (int r = 0; r < 4; ++r) {
            const int row = row0 + r;
            if constexpr (GATE) {
              float gg = gate[(size_t)row * NH + head];
              ((__bf16*)Cp)[(size_t)row * D_ + col] = (__bf16)((v[r] + bc) * gg);
            } else {
              ((float*)Cp)[(size_t)row * D_ + col] = v[r] + bc;
            }
          }
        }
      }
    }
  }
#undef STAGE_HALF
#undef LOAD_BV
#undef LOAD_AV
#undef MFMA_PHASE
#undef WAITLGKM
}

extern "C" void kernel_launch(void* const* d_in, const int* in_sizes, int n_in,
                              void* d_out, int out_size, void* d_ws, size_t ws_size,
                              hipStream_t stream) {
  const float* hs  = (const float*)d_in[0];   // [16,1,1024]
  const float* kvs = (const float*)d_in[1];   // [16,4096,1024]
  const float* Wq  = (const float*)d_in[2];
  const float* bq  = (const float*)d_in[3];
  const float* Wk  = (const float*)d_in[4];
  const float* bk  = (const float*)d_in[5];
  const float* Wv  = (const float*)d_in[6];
  const float* bv  = (const float*)d_in[7];
  const float* Wo  = (const float*)d_in[8];
  const float* bo  = (const float*)d_in[9];
  float* out = (float*)d_out;

  char* w = (char*)d_ws;
  __bf16* ctx  = (__bf16*)w;  w += (size_t)NROWS * D_ * 2;    // 128 MB gated context (bf16)
  float*  attn = (float*)w;   w += (size_t)NROWS * NH * 4;    // 4 MB gate [row][head]
  __bf16* WvB  = (__bf16*)w;  w += (size_t)D_ * D_ * 2;       // 2 MB
  __bf16* WoB  = (__bf16*)w;  w += (size_t)D_ * D_ * 2;       // 2 MB
  __bf16* whi  = (__bf16*)w;  w += (size_t)B_ * NH * D_ * 2;  // 512 KB
  __bf16* wlo  = (__bf16*)w;  w += (size_t)B_ * NH * D_ * 2;  // 512 KB
  float*  cbuf = (float*)w;   w += B_ * NH * 4;               // 1 KB

  // bf16 copy of kvs lives in d_out (128 MB of its 256 MB); written by
  // scores_mfma (== bf16(kvs) exactly), consumed by GEMM1, then fully
  // overwritten by GEMM2's epilogue. No cross-call state.
  __bf16* kvsB = (__bf16*)d_out;

  conv_w_kernel<<<2048, 256, 0, stream>>>(Wv, Wo, WvB, WoB);
  wqeff_kernel<<<dim3(NH, B_), 256, 0, stream>>>(hs, Wq, bq, Wk, bk, whi, wlo, cbuf);
  scores_mfma_kernel<<<dim3(KL / 64, B_), 512, 0, stream>>>(kvs, whi, wlo, cbuf, attn, kvsB);
  gemm_nt<true ><<<1024, 512, 0, stream>>>(kvsB, WvB, bv, attn, ctx);
  gemm_nt<false><<<1024, 512, 0, stream>>>(ctx, WoB, bo, (const float*)nullptr, (void*)out);
}